// Round 5
// baseline (656.097 us; speedup 1.0000x reference)
//
#include <hip/hip_runtime.h>

// CustomWeightedTensorProduct: Z=100000 rows, per row:
//   x1[64]  = s1_0[16] ++ s1_1[16][3]
//   x2[4]   = s2_0 ++ s2_1[3]
//   w[1280] = 5 segments of [u=16][wout=16]
//   out[64] = out0[16] ++ out1[wout=16][i=3]
// Pure streaming, memory-bound. One wave per row; lane (u=lane>>2, c=lane&3)
// computes partials for outputs 4c..4c+3 at its u; reduce-scatter butterfly
// (15 shuffles) leaves one final value per lane -> one coalesced 64-lane store.
// 2-set ping-pong software pipeline: no register rotation, so compute of set A
// only waits on A's loads while B's (and the next A's) stay in flight.

typedef float f32x4 __attribute__((ext_vector_type(4)));

struct RowRegs {
    f32x4 w0, w1, w2, w3, w4;
    f32x4 x2v;
    float xa, xb, xc, xd;
};

__global__ __launch_bounds__(256, 4) void ctp_kernel(
    const float* __restrict__ x1,
    const float* __restrict__ x2,
    const float* __restrict__ w,
    float* __restrict__ out,
    int Z)
{
    const int lane = threadIdx.x & 63;
    const int wid  = threadIdx.x >> 6;
    const int gwave  = blockIdx.x * (blockDim.x >> 6) + wid;
    const int nwaves = gridDim.x * (blockDim.x >> 6);

    const int u = lane >> 2;   // u-group (16 of them, 4 lanes each)
    const int c = lane & 3;    // wout block: weights cover wout=4c..4c+3

    const float inv32 = 0.17677669529663687f;   // 1/sqrt(32)
    const float inv48 = 0.14433756729740643f;   // 1/sqrt(48)
    const float inv3  = 0.57735026918962576f;   // 1/sqrt(3)
    const float inv2  = 0.70710678118654752f;   // 1/sqrt(2)

    // Final output index this lane owns after reduce-scatter (permutation of 0..63).
    const int off = (u < 4) ? (4*c + u) : (12*c + 12 + u);
    const int ub0 = u & 1, ub1 = (u >> 1) & 1, ub2 = (u >> 2) & 1, ub3 = (u >> 3) & 1;

    auto load_row = [&](RowRegs& r, int row) {
        const f32x4* wr = (const f32x4*)(w + (size_t)row * 1280) + lane;
        r.w0 = __builtin_nontemporal_load(wr);
        r.w1 = __builtin_nontemporal_load(wr + 64);
        r.w2 = __builtin_nontemporal_load(wr + 128);
        r.w3 = __builtin_nontemporal_load(wr + 192);
        r.w4 = __builtin_nontemporal_load(wr + 256);
        const float* x1r = x1 + (size_t)row * 64;
        r.xa = x1r[u];
        r.xb = x1r[16 + 3*u];
        r.xc = x1r[17 + 3*u];
        r.xd = x1r[18 + 3*u];
        r.x2v = *(const f32x4*)(x2 + (size_t)row * 4);
    };

    auto compute_row = [&](const RowRegs& r, int row) {
        const float s20 = r.x2v.x, s21_0 = r.x2v.y, s21_1 = r.x2v.z, s21_2 = r.x2v.w;
        const float s10 = r.xa, s11_0 = r.xb, s11_1 = r.xc, s11_2 = r.xd;

        const float ka  = s10 * s20 * inv32;
        const float kd  = (s11_0*s21_0 + s11_1*s21_1 + s11_2*s21_2) * (inv3 * inv32);
        const float kb0 = s10 * s21_0 * inv48;
        const float kb1 = s10 * s21_1 * inv48;
        const float kb2 = s10 * s21_2 * inv48;
        const float kc0 = s11_0 * s20 * inv48;
        const float kc1 = s11_1 * s20 * inv48;
        const float kc2 = s11_2 * s20 * inv48;
        const float sc  = inv2 * inv48;
        const float ke0 = (s11_1*s21_2 - s11_2*s21_1) * sc;
        const float ke1 = (s11_2*s21_0 - s11_0*s21_2) * sc;
        const float ke2 = (s11_0*s21_1 - s11_1*s21_0) * sc;

        float v[16];
        #pragma unroll
        for (int j = 0; j < 4; ++j) {
            v[j]         = r.w0[j]*ka  + r.w3[j]*kd;
            v[4 + 3*j+0] = r.w1[j]*kb0 + r.w2[j]*kc0 + r.w4[j]*ke0;
            v[4 + 3*j+1] = r.w1[j]*kb1 + r.w2[j]*kc1 + r.w4[j]*ke1;
            v[4 + 3*j+2] = r.w1[j]*kb2 + r.w2[j]*kc2 + r.w4[j]*ke2;
        }

        // Reduce-scatter butterfly over the 16 u-lanes (stride 4).
        float a[8];
        #pragma unroll
        for (int m = 0; m < 8; ++m) {
            const float keep = ub0 ? v[2*m+1] : v[2*m];
            const float send = ub0 ? v[2*m]   : v[2*m+1];
            a[m] = keep + __shfl_xor(send, 4, 64);
        }
        float b[4];
        #pragma unroll
        for (int m = 0; m < 4; ++m) {
            const float keep = ub1 ? a[2*m+1] : a[2*m];
            const float send = ub1 ? a[2*m]   : a[2*m+1];
            b[m] = keep + __shfl_xor(send, 8, 64);
        }
        float e[2];
        #pragma unroll
        for (int m = 0; m < 2; ++m) {
            const float keep = ub2 ? b[2*m+1] : b[2*m];
            const float send = ub2 ? b[2*m]   : b[2*m+1];
            e[m] = keep + __shfl_xor(send, 16, 64);
        }
        const float keep = ub3 ? e[1] : e[0];
        const float send = ub3 ? e[0] : e[1];
        const float d = keep + __shfl_xor(send, 32, 64);
        __builtin_nontemporal_store(d, out + (size_t)row * 64 + off);
    };

    int rA = gwave;
    if (rA >= Z) return;
    RowRegs A, B;
    load_row(A, rA);

    int rB = rA + nwaves;
    bool haveB = (rB < Z);
    if (haveB) load_row(B, rB);

    while (true) {
        // Compute A (waits only A's loads; B's remain in flight).
        compute_row(A, rA);
        if (!haveB) break;

        // A's registers are free: issue the row after B into them.
        const int rA2 = rB + nwaves;
        const bool haveA2 = (rA2 < Z);
        if (haveA2) load_row(A, rA2);

        // Compute B (waits only B's loads; A2's remain in flight).
        compute_row(B, rB);
        if (!haveA2) break;
        rA = rA2;

        const int rB2 = rA2 + nwaves;
        haveB = (rB2 < Z);
        if (haveB) load_row(B, rB2);
        rB = rB2;
    }
}

extern "C" void kernel_launch(void* const* d_in, const int* in_sizes, int n_in,
                              void* d_out, int out_size, void* d_ws, size_t ws_size,
                              hipStream_t stream) {
    const float* x1 = (const float*)d_in[0];
    const float* x2 = (const float*)d_in[1];
    const float* w  = (const float*)d_in[2];
    float* out = (float*)d_out;

    const int Z = in_sizes[1] / 4;   // x2 is (Z,4)

    // 2048 blocks x 4 waves = 8192 waves, grid-stride (~12 rows/wave).
    hipLaunchKernelGGL(ctp_kernel, dim3(2048), dim3(256), 0, stream,
                       x1, x2, w, out, Z);
}